// Round 6
// baseline (18.784 us; speedup 1.0000x reference)
//
#include <hip/hip_runtime.h>

// Problem constants (match reference)
constexpr int Bc = 128;
constexpr int Nc = 256;
constexpr int Hc = 272;
constexpr int Wc = 152;
constexpr int RMAXc = 8;
constexpr int HWc = Hc * Wc;

constexpr int SPLIT = 8;          // row chunks per batch image
constexpr int CH    = Hc / SPLIT; // 34 rows per chunk
constexpr int W4    = Wc / 4;     // 38 float4 per row

// One block per (batch, row-chunk); every output byte owned by exactly one
// block (no memset, no global atomics). Front-end is a 2-round dependency
// chain: {mask, index} coalesced -> {x-gather, y-gather, wh} in parallel
// (predicated on mask only) -> math -> LDS compaction list.
__global__ __launch_bounds__(256) void fused_gaussian_kernel(
    const float* __restrict__ flow,   // [B,2,H,W]
    const float* __restrict__ wh,     // [B,N,4]
    const int*   __restrict__ mask,   // [B,N]
    const int*   __restrict__ index,  // [B,N]
    float*       __restrict__ hm)     // [B,H,W]
{
    __shared__ int   s_hm[CH * Wc];   // 20672 B
    __shared__ int   s_xi[Nc], s_yi[Nc], s_ri[Nc];
    __shared__ float s_in[Nc];        // 1/dn reciprocal
    __shared__ int   s_n;

    const int tid   = threadIdx.x;
    const int b     = blockIdx.x >> 3;
    const int chunk = blockIdx.x & 7;
    const int rowLo = chunk * CH;
    const int rowHi = rowLo + CH;

    if (tid == 0) s_n = 0;

    // ---- Round 1: coalesced mask + index in parallel ----
    const int obj = b * Nc + tid;
    const int mk  = mask[obj];
    const int idx = index[obj];

    // ---- Round 2: both flow planes + wh, issued together ----
    float x = -1.0f, y = -1.0f, w = 0.0f, h = 0.0f;
    if (mk != 0) {
        x = flow[(b * 2 + 0) * HWc + idx];
        y = flow[(b * 2 + 1) * HWc + idx];
        const float4 whv = *reinterpret_cast<const float4*>(wh + obj * 4);
        w = whv.x + whv.z;
        h = whv.y + whv.w;
    }

    // Zero the slab while the gathers are in flight (vectorized b128).
    {
        int4* s4 = reinterpret_cast<int4*>(s_hm);
        const int4 z = make_int4(0, 0, 0, 0);
        for (int i = tid; i < CH * W4; i += 256) s4[i] = z;
    }

    if (h > 0.0f && w > 0.0f && x > 0.0f && y > 0.0f &&
        x < 152.0f && y < 272.0f) {
        const int yi = (int)floorf(y);
        // conservative chunk test (RMAX bound) before the radius math
        if (yi + RMAXc >= rowLo && yi - RMAXc <= rowHi - 1) {
            // gaussian_radius(ceil(h), ceil(w)) — f32 op order as reference
            const float height = ceilf(h);
            const float width  = ceilf(w);

            const float b1  = height + width;
            const float c1  = width * height * 0.3f / 1.7f;
            const float sq1 = sqrtf(b1 * b1 - 4.0f * c1);
            const float r1  = (b1 + sq1) * 0.5f;

            const float b2  = 2.0f * (height + width);
            const float c2  = 0.3f * width * height;
            const float sq2 = sqrtf(b2 * b2 - 16.0f * c2);
            const float r2  = (b2 + sq2) * 0.5f;

            const float b3  = -1.4f * (height + width);
            const float c3  = -0.3f * width * height;
            const float sq3 = sqrtf(b3 * b3 - 11.2f * c3);
            const float r3  = (b3 + sq3) * 0.5f;

            float radius = fminf(fminf(r1, r2), r3);
            radius = fmaxf(radius, 0.0f);
            if (radius >= 0.0f) {            // NaN guard
                const float rf = floorf(radius);   // unclamped: sigma uses this
                int ri = (int)rf;
                if (ri > RMAXc) ri = RMAXc;        // paint window bound (ref grid is ±8)
                // precise window-row intersection
                if (yi + ri >= rowLo && yi - ri <= rowHi - 1) {
                    const float sigma = (2.0f * rf + 1.0f) / 6.0f;
                    const int pos = atomicAdd(&s_n, 1);
                    s_xi[pos] = (int)floorf(x);
                    s_yi[pos] = yi;
                    s_ri[pos] = ri;
                    s_in[pos] = 1.0f / (2.0f * sigma * sigma);
                }
            }
        }
    }
    __syncthreads();

    // ---- Scatter: wave-per-listed-object ----
    const int wave = tid >> 6;
    const int lane = tid & 63;
    const int nobj = s_n;
    for (int o = wave; o < nobj; o += 4) {
        const int   ri = s_ri[o];
        const int   xi = s_xi[o];
        const int   yi = s_yi[o];
        const float in_dn = s_in[o];

        int dyLo = -ri, dyHi = ri;
        if (yi + dyLo < rowLo)     dyLo = rowLo - yi;
        if (yi + dyHi > rowHi - 1) dyHi = rowHi - 1 - yi;

        const unsigned dw    = 2 * ri + 1;
        const int      ncell = (dyHi - dyLo + 1) * (int)dw;
        // magic division: exact for dw<=17, c<=288
        const unsigned m = 2097152u / dw + 1u;     // 2^21
        for (int c = lane; c < ncell; c += 64) {
            const unsigned q  = ((unsigned)c * m) >> 21;   // c / dw
            const int      dy = dyLo + (int)q;
            const int      dx = (int)((unsigned)c - q * dw) - ri;
            const int      xx = xi + dx;
            if (xx < 0 || xx >= Wc) continue;
            const float dist2 = (float)(dx * dx + dy * dy);
            const float g = __expf(-dist2 * in_dn);
            if (g < 2e-15f) continue;      // max(0) no-op on zeroed slab
            // g >= 0 so int-punned max == float max
            atomicMax(&s_hm[(yi + dy - rowLo) * Wc + xx], __float_as_int(g));
        }
    }
    __syncthreads();

    // ---- Coalesced float4 stream-out (each byte written exactly once) ----
    {
        float4* out4 = reinterpret_cast<float4*>(hm + (size_t)(b * Hc + rowLo) * Wc);
        const float4* l4 = reinterpret_cast<const float4*>(s_hm);
        for (int i = tid; i < CH * W4; i += 256) out4[i] = l4[i];
    }
}

extern "C" void kernel_launch(void* const* d_in, const int* in_sizes, int n_in,
                              void* d_out, int out_size, void* d_ws, size_t ws_size,
                              hipStream_t stream) {
    const float* flow  = (const float*)d_in[0];  // [B,2,H,W] f32
    const float* wh    = (const float*)d_in[1];  // [B,N,4]   f32
    const int*   mask  = (const int*)d_in[2];    // [B,N]     i32
    const int*   index = (const int*)d_in[3];    // [B,N]     i32
    float* hm = (float*)d_out;                   // [B,1,H,W] f32

    // 128 batches x 8 row-chunks = 1024 blocks (4/CU, fully resident).
    fused_gaussian_kernel<<<Bc * SPLIT, 256, 0, stream>>>(flow, wh, mask, index, hm);
}

// Round 7
// 17.065 us; speedup vs baseline: 1.1007x; 1.1007x over previous
//
#include <hip/hip_runtime.h>

// Problem constants (match reference)
constexpr int Bc = 128;
constexpr int Nc = 256;
constexpr int Hc = 272;
constexpr int Wc = 152;
constexpr int RMAXc = 8;
constexpr int HWc = Hc * Wc;

constexpr int SPLIT = 8;          // row chunks per batch image
constexpr int CH    = Hc / SPLIT; // 34 rows per chunk
constexpr int W4    = Wc / 4;     // 38 float4 per row

// One block per (batch, row-chunk); every output byte owned by exactly one
// block (no memset, no global atomics). Predicated, deferred front-end:
//   {mask, index} coalesced (unconditional)
//   -> y-plane gather (only if mask)            [~128/256 lanes]
//   -> conservative RMAX y-window test
//   -> x-plane gather + wh + radius math        [~16/256 lanes]
//   -> precise test -> LDS compaction list.
// Round-6 lesson: making x/wh unconditional on mask costs +8 MB scattered
// lines and regressed 0.9 us; keep them behind the y-window test.
__global__ __launch_bounds__(256) void fused_gaussian_kernel(
    const float* __restrict__ flow,   // [B,2,H,W]
    const float* __restrict__ wh,     // [B,N,4]
    const int*   __restrict__ mask,   // [B,N]
    const int*   __restrict__ index,  // [B,N]
    float*       __restrict__ hm)     // [B,H,W]
{
    __shared__ int   s_hm[CH * Wc];   // 20672 B
    __shared__ int   s_xi[Nc], s_yi[Nc], s_ri[Nc];
    __shared__ float s_in[Nc];        // reciprocal of 2*sigma^2
    __shared__ int   s_n;

    const int tid   = threadIdx.x;
    const int b     = blockIdx.x >> 3;
    const int chunk = blockIdx.x & 7;
    const int rowLo = chunk * CH;
    const int rowHi = rowLo + CH;

    if (tid == 0) s_n = 0;

    // ---- Round 1: coalesced mask + index (both unconditional, adjacent) ----
    const int obj = b * Nc + tid;
    const int mk  = mask[obj];
    const int idx = index[obj];

    // ---- Round 2: y-plane gather only (predicated on mask) ----
    float y = -1.0f;
    if (mk != 0) {
        y = flow[(b * 2 + 1) * HWc + idx];
    }

    // Zero the slab while the y-gather is in flight (vectorized b128).
    {
        int4* s4 = reinterpret_cast<int4*>(s_hm);
        const int4 z = make_int4(0, 0, 0, 0);
        for (int i = tid; i < CH * W4; i += 256) s4[i] = z;
    }

    if (y > 0.0f && y < 272.0f) {
        const int yi = (int)floorf(y);
        // conservative chunk test (RMAX bound) before any more loads
        if (yi + RMAXc >= rowLo && yi - RMAXc <= rowHi - 1) {
            // ---- Round 3: x-plane gather + wh (only ~1/8 of masked lanes) ----
            const float4 whv = *reinterpret_cast<const float4*>(wh + obj * 4);
            const float x = flow[(b * 2 + 0) * HWc + idx];
            const float w = whv.x + whv.z;
            const float h = whv.y + whv.w;
            if (h > 0.0f && w > 0.0f && x > 0.0f && x < 152.0f) {
                // gaussian_radius(ceil(h), ceil(w)) — f32 op order as reference
                const float height = ceilf(h);
                const float width  = ceilf(w);

                const float b1  = height + width;
                const float c1  = width * height * 0.3f / 1.7f;
                const float sq1 = sqrtf(b1 * b1 - 4.0f * c1);
                const float r1  = (b1 + sq1) * 0.5f;

                const float b2  = 2.0f * (height + width);
                const float c2  = 0.3f * width * height;
                const float sq2 = sqrtf(b2 * b2 - 16.0f * c2);
                const float r2  = (b2 + sq2) * 0.5f;

                const float b3  = -1.4f * (height + width);
                const float c3  = -0.3f * width * height;
                const float sq3 = sqrtf(b3 * b3 - 11.2f * c3);
                const float r3  = (b3 + sq3) * 0.5f;

                float radius = fminf(fminf(r1, r2), r3);
                radius = fmaxf(radius, 0.0f);
                if (radius >= 0.0f) {            // NaN guard
                    const float rf = floorf(radius);   // sigma uses unclamped rf
                    int ri = (int)rf;
                    if (ri > RMAXc) ri = RMAXc;        // ref paint grid is ±8
                    // precise window-row intersection
                    if (yi + ri >= rowLo && yi - ri <= rowHi - 1) {
                        const float sigma = (2.0f * rf + 1.0f) / 6.0f;
                        const int pos = atomicAdd(&s_n, 1);
                        s_xi[pos] = (int)floorf(x);
                        s_yi[pos] = yi;
                        s_ri[pos] = ri;
                        s_in[pos] = 1.0f / (2.0f * sigma * sigma);
                    }
                }
            }
        }
    }
    __syncthreads();

    // ---- Scatter: wave-per-listed-object (list ~20 entries) ----
    const int wave = tid >> 6;
    const int lane = tid & 63;
    const int nobj = s_n;
    for (int o = wave; o < nobj; o += 4) {
        const int   ri = s_ri[o];
        const int   xi = s_xi[o];
        const int   yi = s_yi[o];
        const float in_dn = s_in[o];

        int dyLo = -ri, dyHi = ri;
        if (yi + dyLo < rowLo)     dyLo = rowLo - yi;
        if (yi + dyHi > rowHi - 1) dyHi = rowHi - 1 - yi;

        const unsigned dw    = 2 * ri + 1;
        const int      ncell = (dyHi - dyLo + 1) * (int)dw;
        // magic division: exact for dw<=17, c<=288
        const unsigned m = 2097152u / dw + 1u;     // 2^21
        for (int c = lane; c < ncell; c += 64) {
            const unsigned q  = ((unsigned)c * m) >> 21;   // c / dw
            const int      dy = dyLo + (int)q;
            const int      dx = (int)((unsigned)c - q * dw) - ri;
            const int      xx = xi + dx;
            if (xx < 0 || xx >= Wc) continue;
            const float dist2 = (float)(dx * dx + dy * dy);
            const float g = __expf(-dist2 * in_dn);
            if (g < 2e-15f) continue;      // max(0) no-op on zeroed slab
            // g >= 0 so int-punned max == float max
            atomicMax(&s_hm[(yi + dy - rowLo) * Wc + xx], __float_as_int(g));
        }
    }
    __syncthreads();

    // ---- Coalesced float4 stream-out (each byte written exactly once) ----
    {
        float4* out4 = reinterpret_cast<float4*>(hm + (size_t)(b * Hc + rowLo) * Wc);
        const float4* l4 = reinterpret_cast<const float4*>(s_hm);
        for (int i = tid; i < CH * W4; i += 256) out4[i] = l4[i];
    }
}

extern "C" void kernel_launch(void* const* d_in, const int* in_sizes, int n_in,
                              void* d_out, int out_size, void* d_ws, size_t ws_size,
                              hipStream_t stream) {
    const float* flow  = (const float*)d_in[0];  // [B,2,H,W] f32
    const float* wh    = (const float*)d_in[1];  // [B,N,4]   f32
    const int*   mask  = (const int*)d_in[2];    // [B,N]     i32
    const int*   index = (const int*)d_in[3];    // [B,N]     i32
    float* hm = (float*)d_out;                   // [B,1,H,W] f32

    // 128 batches x 8 row-chunks = 1024 blocks (4/CU, fully resident).
    fused_gaussian_kernel<<<Bc * SPLIT, 256, 0, stream>>>(flow, wh, mask, index, hm);
}

// Round 8
// 14.841 us; speedup vs baseline: 1.2657x; 1.1499x over previous
//
#include <hip/hip_runtime.h>

// Problem constants (match reference)
constexpr int Bc = 128;
constexpr int Nc = 256;
constexpr int Hc = 272;
constexpr int Wc = 152;
constexpr int RMAXc = 8;
constexpr int HWc = Hc * Wc;

constexpr int SPLIT = 4;          // row chunks per batch image
constexpr int CH    = Hc / SPLIT; // 68 rows per chunk
constexpr int W4    = Wc / 4;     // 38 float4 per row
constexpr int NTHR  = 512;        // 8 waves per block, 2 blocks/CU (LDS-limited)

// One block per (batch, row-chunk); every output byte owned by exactly one
// block (no memset, no global atomics). 512 threads: halves the per-batch
// front-end redundancy vs SPLIT=8/256thr while keeping 16 waves/CU.
// Predicated, deferred front-end (round-5/6 lesson: defer x/wh behind the
// conservative y-window test; bundling them with y regressed 0.9 us):
//   {mask, index} coalesced -> y-gather (if mask) -> RMAX window test
//   -> x-gather + wh + radius math (few lanes) -> precise test -> LDS list.
__global__ __launch_bounds__(NTHR, 4) void fused_gaussian_kernel(
    const float* __restrict__ flow,   // [B,2,H,W]
    const float* __restrict__ wh,     // [B,N,4]
    const int*   __restrict__ mask,   // [B,N]
    const int*   __restrict__ index,  // [B,N]
    float*       __restrict__ hm)     // [B,H,W]
{
    __shared__ int   s_hm[CH * Wc];   // 41344 B
    __shared__ int   s_xi[Nc], s_yi[Nc], s_ri[Nc];
    __shared__ float s_in[Nc];        // reciprocal of 2*sigma^2
    __shared__ int   s_n;

    const int tid   = threadIdx.x;
    const int b     = blockIdx.x >> 2;
    const int chunk = blockIdx.x & 3;
    const int rowLo = chunk * CH;
    const int rowHi = rowLo + CH;

    if (tid == 0) s_n = 0;

    // ---- Front-end: one object per thread for tid<256 ----
    int mk = 0, idx = 0, obj = 0;
    if (tid < Nc) {
        obj = b * Nc + tid;
        mk  = mask[obj];              // coalesced, parallel with index
        idx = index[obj];
    }

    float y = -1.0f;
    if (mk != 0) {
        y = flow[(b * 2 + 1) * HWc + idx];   // y-plane gather only
    }

    // Zero the slab with all 512 threads while the y-gather is in flight.
    {
        int4* s4 = reinterpret_cast<int4*>(s_hm);
        const int4 z = make_int4(0, 0, 0, 0);
        for (int i = tid; i < CH * W4; i += NTHR) s4[i] = z;
    }

    if (y > 0.0f && y < 272.0f) {
        const int yi = (int)floorf(y);
        // conservative chunk test (RMAX bound) before any more loads
        if (yi + RMAXc >= rowLo && yi - RMAXc <= rowHi - 1) {
            const float4 whv = *reinterpret_cast<const float4*>(wh + obj * 4);
            const float x = flow[(b * 2 + 0) * HWc + idx];   // x-plane gather
            const float w = whv.x + whv.z;
            const float h = whv.y + whv.w;
            if (h > 0.0f && w > 0.0f && x > 0.0f && x < 152.0f) {
                // gaussian_radius(ceil(h), ceil(w)) — f32 op order as reference
                const float height = ceilf(h);
                const float width  = ceilf(w);

                const float b1  = height + width;
                const float c1  = width * height * 0.3f / 1.7f;
                const float sq1 = sqrtf(b1 * b1 - 4.0f * c1);
                const float r1  = (b1 + sq1) * 0.5f;

                const float b2  = 2.0f * (height + width);
                const float c2  = 0.3f * width * height;
                const float sq2 = sqrtf(b2 * b2 - 16.0f * c2);
                const float r2  = (b2 + sq2) * 0.5f;

                const float b3  = -1.4f * (height + width);
                const float c3  = -0.3f * width * height;
                const float sq3 = sqrtf(b3 * b3 - 11.2f * c3);
                const float r3  = (b3 + sq3) * 0.5f;

                float radius = fminf(fminf(r1, r2), r3);
                radius = fmaxf(radius, 0.0f);
                if (radius >= 0.0f) {            // NaN guard
                    const float rf = floorf(radius);   // sigma uses unclamped rf
                    int ri = (int)rf;
                    if (ri > RMAXc) ri = RMAXc;        // ref paint grid is ±8
                    // precise window-row intersection
                    if (yi + ri >= rowLo && yi - ri <= rowHi - 1) {
                        const float sigma = (2.0f * rf + 1.0f) / 6.0f;
                        const int pos = atomicAdd(&s_n, 1);
                        s_xi[pos] = (int)floorf(x);
                        s_yi[pos] = yi;
                        s_ri[pos] = ri;
                        s_in[pos] = 1.0f / (2.0f * sigma * sigma);
                    }
                }
            }
        }
    }
    __syncthreads();

    // ---- Scatter: wave-per-listed-object (list ~60 entries here) ----
    const int wave = tid >> 6;    // 0..7
    const int lane = tid & 63;
    const int nobj = s_n;
    for (int o = wave; o < nobj; o += NTHR / 64) {
        const int   ri = s_ri[o];
        const int   xi = s_xi[o];
        const int   yi = s_yi[o];
        const float in_dn = s_in[o];

        int dyLo = -ri, dyHi = ri;
        if (yi + dyLo < rowLo)     dyLo = rowLo - yi;
        if (yi + dyHi > rowHi - 1) dyHi = rowHi - 1 - yi;

        const unsigned dw    = 2 * ri + 1;
        const int      ncell = (dyHi - dyLo + 1) * (int)dw;
        // magic division: exact for dw<=17, c<=288
        const unsigned m = 2097152u / dw + 1u;     // 2^21
        for (int c = lane; c < ncell; c += 64) {
            const unsigned q  = ((unsigned)c * m) >> 21;   // c / dw
            const int      dy = dyLo + (int)q;
            const int      dx = (int)((unsigned)c - q * dw) - ri;
            const int      xx = xi + dx;
            if (xx < 0 || xx >= Wc) continue;
            const float dist2 = (float)(dx * dx + dy * dy);
            const float g = __expf(-dist2 * in_dn);
            if (g < 2e-15f) continue;      // max(0) no-op on zeroed slab
            // g >= 0 so int-punned max == float max
            atomicMax(&s_hm[(yi + dy - rowLo) * Wc + xx], __float_as_int(g));
        }
    }
    __syncthreads();

    // ---- Coalesced float4 stream-out (each byte written exactly once) ----
    {
        float4* out4 = reinterpret_cast<float4*>(hm + (size_t)(b * Hc + rowLo) * Wc);
        const float4* l4 = reinterpret_cast<const float4*>(s_hm);
        for (int i = tid; i < CH * W4; i += NTHR) out4[i] = l4[i];
    }
}

extern "C" void kernel_launch(void* const* d_in, const int* in_sizes, int n_in,
                              void* d_out, int out_size, void* d_ws, size_t ws_size,
                              hipStream_t stream) {
    const float* flow  = (const float*)d_in[0];  // [B,2,H,W] f32
    const float* wh    = (const float*)d_in[1];  // [B,N,4]   f32
    const int*   mask  = (const int*)d_in[2];    // [B,N]     i32
    const int*   index = (const int*)d_in[3];    // [B,N]     i32
    float* hm = (float*)d_out;                   // [B,1,H,W] f32

    // 128 batches x 4 row-chunks = 512 blocks x 512 threads (2/CU, 16 waves/CU).
    fused_gaussian_kernel<<<Bc * SPLIT, NTHR, 0, stream>>>(flow, wh, mask, index, hm);
}

// Round 9
// 14.773 us; speedup vs baseline: 1.2715x; 1.0046x over previous
//
#include <hip/hip_runtime.h>

// Problem constants (match reference)
constexpr int Bc = 128;
constexpr int Nc = 256;
constexpr int Hc = 272;
constexpr int Wc = 152;
constexpr int RMAXc = 8;
constexpr int HWc = Hc * Wc;

constexpr int SPLIT = 2;          // row chunks per batch image
constexpr int CH    = Hc / SPLIT; // 136 rows per chunk
constexpr int W4    = Wc / 4;     // 38 float4 per row
constexpr int NTHR  = 1024;       // 16 waves per block, 1 block/CU (LDS-limited)

// One block per (batch, row-chunk); every output byte owned by exactly one
// block (no memset, no global atomics). 256 blocks x 1024 threads = exactly
// 1 block per CU (87 KB LDS), 16 waves/CU. Front-end redundancy is now only
// x2 per batch (was x8 in round 5, x4 in round 8 -> each halving won ~2 us).
// Predicated, deferred front-end (round-6 lesson: defer x/wh behind the
// conservative y-window test):
//   {mask, index} coalesced -> y-gather (if mask) -> RMAX window test
//   -> x-gather + wh + radius math -> precise test -> LDS compaction list.
__global__ __launch_bounds__(NTHR) void fused_gaussian_kernel(
    const float* __restrict__ flow,   // [B,2,H,W]
    const float* __restrict__ wh,     // [B,N,4]
    const int*   __restrict__ mask,   // [B,N]
    const int*   __restrict__ index,  // [B,N]
    float*       __restrict__ hm)     // [B,H,W]
{
    __shared__ int   s_hm[CH * Wc];   // 82688 B (gfx950 allows up to 160 KiB/WG)
    __shared__ int   s_xi[Nc], s_yi[Nc], s_ri[Nc];
    __shared__ float s_in[Nc];        // reciprocal of 2*sigma^2
    __shared__ int   s_n;

    const int tid   = threadIdx.x;
    const int b     = blockIdx.x >> 1;
    const int chunk = blockIdx.x & 1;
    const int rowLo = chunk * CH;
    const int rowHi = rowLo + CH;

    if (tid == 0) s_n = 0;

    // ---- Front-end: one object per thread for tid<256 ----
    int mk = 0, idx = 0, obj = 0;
    if (tid < Nc) {
        obj = b * Nc + tid;
        mk  = mask[obj];              // coalesced, parallel with index
        idx = index[obj];
    }

    float y = -1.0f;
    if (mk != 0) {
        y = flow[(b * 2 + 1) * HWc + idx];   // y-plane gather only
    }

    // Zero the slab with all 1024 threads while the y-gather is in flight.
    {
        int4* s4 = reinterpret_cast<int4*>(s_hm);
        const int4 z = make_int4(0, 0, 0, 0);
        for (int i = tid; i < CH * W4; i += NTHR) s4[i] = z;
    }

    if (y > 0.0f && y < 272.0f) {
        const int yi = (int)floorf(y);
        // conservative chunk test (RMAX bound) before any more loads
        if (yi + RMAXc >= rowLo && yi - RMAXc <= rowHi - 1) {
            const float4 whv = *reinterpret_cast<const float4*>(wh + obj * 4);
            const float x = flow[(b * 2 + 0) * HWc + idx];   // x-plane gather
            const float w = whv.x + whv.z;
            const float h = whv.y + whv.w;
            if (h > 0.0f && w > 0.0f && x > 0.0f && x < 152.0f) {
                // gaussian_radius(ceil(h), ceil(w)) — f32 op order as reference
                const float height = ceilf(h);
                const float width  = ceilf(w);

                const float b1  = height + width;
                const float c1  = width * height * 0.3f / 1.7f;
                const float sq1 = sqrtf(b1 * b1 - 4.0f * c1);
                const float r1  = (b1 + sq1) * 0.5f;

                const float b2  = 2.0f * (height + width);
                const float c2  = 0.3f * width * height;
                const float sq2 = sqrtf(b2 * b2 - 16.0f * c2);
                const float r2  = (b2 + sq2) * 0.5f;

                const float b3  = -1.4f * (height + width);
                const float c3  = -0.3f * width * height;
                const float sq3 = sqrtf(b3 * b3 - 11.2f * c3);
                const float r3  = (b3 + sq3) * 0.5f;

                float radius = fminf(fminf(r1, r2), r3);
                radius = fmaxf(radius, 0.0f);
                if (radius >= 0.0f) {            // NaN guard
                    const float rf = floorf(radius);   // sigma uses unclamped rf
                    int ri = (int)rf;
                    if (ri > RMAXc) ri = RMAXc;        // ref paint grid is ±8
                    // precise window-row intersection
                    if (yi + ri >= rowLo && yi - ri <= rowHi - 1) {
                        const float sigma = (2.0f * rf + 1.0f) / 6.0f;
                        const int pos = atomicAdd(&s_n, 1);
                        s_xi[pos] = (int)floorf(x);
                        s_yi[pos] = yi;
                        s_ri[pos] = ri;
                        s_in[pos] = 1.0f / (2.0f * sigma * sigma);
                    }
                }
            }
        }
    }
    __syncthreads();

    // ---- Scatter: wave-per-listed-object (list ~120 entries in chunk 0) ----
    const int wave = tid >> 6;    // 0..15
    const int lane = tid & 63;
    const int nobj = s_n;
    for (int o = wave; o < nobj; o += NTHR / 64) {
        const int   ri = s_ri[o];
        const int   xi = s_xi[o];
        const int   yi = s_yi[o];
        const float in_dn = s_in[o];

        int dyLo = -ri, dyHi = ri;
        if (yi + dyLo < rowLo)     dyLo = rowLo - yi;
        if (yi + dyHi > rowHi - 1) dyHi = rowHi - 1 - yi;

        const unsigned dw    = 2 * ri + 1;
        const int      ncell = (dyHi - dyLo + 1) * (int)dw;
        // magic division: exact for dw<=17, c<=288
        const unsigned m = 2097152u / dw + 1u;     // 2^21
        for (int c = lane; c < ncell; c += 64) {
            const unsigned q  = ((unsigned)c * m) >> 21;   // c / dw
            const int      dy = dyLo + (int)q;
            const int      dx = (int)((unsigned)c - q * dw) - ri;
            const int      xx = xi + dx;
            if (xx < 0 || xx >= Wc) continue;
            const float dist2 = (float)(dx * dx + dy * dy);
            const float g = __expf(-dist2 * in_dn);
            if (g < 2e-15f) continue;      // max(0) no-op on zeroed slab
            // g >= 0 so int-punned max == float max
            atomicMax(&s_hm[(yi + dy - rowLo) * Wc + xx], __float_as_int(g));
        }
    }
    __syncthreads();

    // ---- Coalesced float4 stream-out (each byte written exactly once) ----
    {
        float4* out4 = reinterpret_cast<float4*>(hm + (size_t)(b * Hc + rowLo) * Wc);
        const float4* l4 = reinterpret_cast<const float4*>(s_hm);
        for (int i = tid; i < CH * W4; i += NTHR) out4[i] = l4[i];
    }
}

extern "C" void kernel_launch(void* const* d_in, const int* in_sizes, int n_in,
                              void* d_out, int out_size, void* d_ws, size_t ws_size,
                              hipStream_t stream) {
    const float* flow  = (const float*)d_in[0];  // [B,2,H,W] f32
    const float* wh    = (const float*)d_in[1];  // [B,N,4]   f32
    const int*   mask  = (const int*)d_in[2];    // [B,N]     i32
    const int*   index = (const int*)d_in[3];    // [B,N]     i32
    float* hm = (float*)d_out;                   // [B,1,H,W] f32

    // 128 batches x 2 row-chunks = 256 blocks x 1024 threads (1/CU, 16 waves/CU).
    fused_gaussian_kernel<<<Bc * SPLIT, NTHR, 0, stream>>>(flow, wh, mask, index, hm);
}